// Round 2
// baseline (1348.215 us; speedup 1.0000x reference)
//
#include <hip/hip_runtime.h>
#include <stdint.h>

// GraphSAGE fused layer, MI355X (gfx950). All tensors fp32 (per reference).
// N=16384, D_IN=D_OUT=64. adj is a binary 0/1 fp32 mask, avg degree ~32.
// adj = 1.074 GB dominates: stream each row exactly once (floor ~170 us),
// sparse-scan nonzero columns into an LDS index list (~33/row), gather X
// rows from L2, then fused GEMV + ReLU + row L2-normalize. 1 block = 1 row.

#define NROWS  16384
#define DDIM   64
#define MAXNNZ 256   // avg deg 32, std ~5.7; 256 is ~40 sigma — safe

__global__ __launch_bounds__(256) void sage_fused(
    const float* __restrict__ X,     // (N, 64)
    const float* __restrict__ adj,   // (N, N)
    const float* __restrict__ W,     // (128, 64) row-major
    const float* __restrict__ bias,  // (64,)
    float* __restrict__ out)         // (N, 64)
{
    __shared__ float sW[128 * 64];   // 32 KB staged weights
    __shared__ float scat[128];      // [X_i | h_neigh]
    __shared__ float spart[4][64];   // split-k partials (reused twice)
    __shared__ float sb[64];
    __shared__ int   slist[MAXNNZ];
    __shared__ int   scnt;

    const int tid = threadIdx.x;
    const int row = blockIdx.x;
    const int d   = tid & 63;   // dim / output index
    const int g   = tid >> 6;   // wave id 0..3 (split-k)

    if (tid == 0) scnt = 0;

    // Issue the full adj-row load first: 256 thr x 16 x uint4 = 64 KB row.
    const uint4* rowp = reinterpret_cast<const uint4*>(adj + (size_t)row * NROWS);
    uint4 v[16];
#pragma unroll
    for (int it = 0; it < 16; ++it) v[it] = rowp[it * 256 + tid];

    // Stage W (32 KB) + bias into LDS while adj loads are in flight.
    {
        const float4* wp  = reinterpret_cast<const float4*>(W);
        float4*       swp = reinterpret_cast<float4*>(sW);
#pragma unroll
        for (int it = 0; it < 8; ++it) swp[it * 256 + tid] = wp[it * 256 + tid];
        if (tid < 64) sb[tid] = bias[tid];
    }
    __syncthreads();   // scnt=0 visible before any push

    // Sparse scan: fp32 entries are exactly 0.0f (all-zero bits) or 1.0f.
#pragma unroll
    for (int it = 0; it < 16; ++it) {
        const uint4 vv = v[it];
        if (vv.x | vv.y | vv.z | vv.w) {           // ~0.8% of chunks taken
            const int base = (it * 256 + tid) * 4;
            const uint32_t w4[4] = { vv.x, vv.y, vv.z, vv.w };
#pragma unroll
            for (int j = 0; j < 4; ++j) {
                if (w4[j]) {
                    const int p = atomicAdd(&scnt, 1);
                    if (p < MAXNNZ) slist[p] = base + j;
                }
            }
        }
    }
    __syncthreads();
    const int nnz = min(scnt, MAXNNZ);

    // Gather-accumulate neighbor X rows; each wave reads one contiguous
    // 256 B X row per iteration (coalesced; X is 4 MB -> L2/LLC resident).
    float acc = 0.0f;
    for (int k = g; k < nnz; k += 4) {
        const int j = slist[k];                     // LDS broadcast
        acc += X[(size_t)j * DDIM + d];
    }
    spart[g][d] = acc;
    __syncthreads();

    if (tid < 64) {
        const float xi  = X[(size_t)row * DDIM + d];
        const float hs  = spart[0][d] + spart[1][d] + spart[2][d] + spart[3][d] + xi;
        const float deg = (float)scnt + 1.0f;       // rowsum(adj)+1, >=1 always
        scat[d]        = xi;
        scat[DDIM + d] = hs / deg;
    }
    __syncthreads();

    // GEMV: z[o] = b[o] + sum_k cat[k] * W[k][o], split-k over 4 waves.
    float zp = 0.0f;
#pragma unroll
    for (int kk = 0; kk < 32; ++kk) {
        const int k = (g << 5) + kk;
        zp = fmaf(scat[k], sW[k * 64 + d], zp);    // scat: broadcast; sW: 2 lanes/bank (free)
    }
    spart[g][d] = zp;
    __syncthreads();

    // Epilogue: bias + reduce, ReLU, row L2-normalize, fp32 store.
    if (tid < 64) {
        float z = sb[d] + spart[0][d] + spart[1][d] + spart[2][d] + spart[3][d];
        z = fmaxf(z, 0.0f);
        float s = z * z;
#pragma unroll
        for (int off = 32; off >= 1; off >>= 1) s += __shfl_xor(s, off);
        const float inv = 1.0f / fmaxf(sqrtf(s), 1e-12f);
        out[(size_t)row * DDIM + d] = z * inv;
    }
}

extern "C" void kernel_launch(void* const* d_in, const int* in_sizes, int n_in,
                              void* d_out, int out_size, void* d_ws, size_t ws_size,
                              hipStream_t stream) {
    const float* X   = (const float*)d_in[0];
    const float* adj = (const float*)d_in[1];
    const float* W   = (const float*)d_in[2];
    const float* b   = (const float*)d_in[3];
    float* out = (float*)d_out;
    sage_fused<<<NROWS, 256, 0, stream>>>(X, adj, W, b, out);
}

// Round 4
// 1336.900 us; speedup vs baseline: 1.0085x; 1.0085x over previous
//
#include <hip/hip_runtime.h>
#include <stdint.h>

// GraphSAGE fused layer, MI355X (gfx950). All tensors fp32.
// N=16384, D=64. adj = binary fp32 mask (1.074 GB) -> stream once, floor ~170us.
// Design: ONE WAVE PER ROW, no __syncthreads. 2048 blocks x 4 waves, 2 rows/wave.
// Per row: prefetch-pipelined nontemporal scan of the 64 KB adj row ->
// per-wave LDS nonzero index list (~33 entries) -> gather X rows (L2-hot) ->
// GEMV from L2-resident W -> ReLU -> 64-lane L2-normalize -> store.

#define NROWS   16384
#define DDIM    64
#define MAXNNZ  256       // deg ~ Binom(16384, 32/16384): mean 32, sigma 5.7
#define NBLOCKS 2048
#define TOTAL_WAVES (NBLOCKS * 4)            // 8192
#define ROWS_PER_WAVE (NROWS / TOTAL_WAVES)  // 2

typedef uint32_t u32x4 __attribute__((ext_vector_type(4)));  // native vec: OK for nontemporal builtin

__global__ __launch_bounds__(256, 4) void sage_fused(
    const float* __restrict__ X,     // (N, 64)
    const float* __restrict__ adj,   // (N, N)
    const float* __restrict__ W,     // (128, 64) row-major, L2-hot (32 KB)
    const float* __restrict__ bias,  // (64,)
    float* __restrict__ out)         // (N, 64)
{
    __shared__ int   slist[4][MAXNNZ];   // per-wave nonzero column list
    __shared__ int   scnt[4];
    __shared__ float scat[4][2 * DDIM];  // per-wave [x_i | h_neigh]

    const int tid  = threadIdx.x;
    const int lane = tid & 63;
    const int w    = tid >> 6;
    const int gw   = blockIdx.x * 4 + w;   // global wave id, 0..8191

    const float bv = bias[lane];           // broadcast, L2-hot

    for (int r = 0; r < ROWS_PER_WAVE; ++r) {
        const int row = gw + r * TOTAL_WAVES;

        if (lane == 0) scnt[w] = 0;
        __builtin_amdgcn_wave_barrier();   // scheduling fence (free)

        // ---- Scan the 64 KB adj row: 16 stages x (4 x 16B/lane), prefetched.
        const u32x4* rowp = reinterpret_cast<const u32x4*>(adj + (size_t)row * NROWS);
        u32x4 c[4], n[4];
#pragma unroll
        for (int q = 0; q < 4; ++q)
            c[q] = __builtin_nontemporal_load(&rowp[q * 64 + lane]);

#pragma unroll 1
        for (int s = 0; s < 16; ++s) {
            if (s < 15) {
#pragma unroll
                for (int q = 0; q < 4; ++q)
                    n[q] = __builtin_nontemporal_load(&rowp[(s + 1) * 256 + q * 64 + lane]);
            }
#pragma unroll
            for (int q = 0; q < 4; ++q) {
                const u32x4 vv = c[q];
                if (vv.x | vv.y | vv.z | vv.w) {          // fp32 0.0f == all-zero bits
                    const int base = (s * 256 + q * 64 + lane) * 4;
                    const uint32_t w4[4] = { vv.x, vv.y, vv.z, vv.w };
#pragma unroll
                    for (int j = 0; j < 4; ++j) {
                        if (w4[j]) {
                            const int p = atomicAdd(&scnt[w], 1);
                            if (p < MAXNNZ) slist[w][p] = base + j;
                        }
                    }
                }
            }
#pragma unroll
            for (int q = 0; q < 4; ++q) c[q] = n[q];
        }
        __builtin_amdgcn_wave_barrier();

        const int nnz = scnt[w];           // DS ops are in-order per wave
        const int cn  = (nnz < MAXNNZ) ? nnz : MAXNNZ;

        // ---- Gather-accumulate neighbor X rows (coalesced 256 B reads, cache-hot).
        float acc = 0.0f;
        int k = 0;
        for (; k + 4 <= cn; k += 4) {
            const int j0 = slist[w][k], j1 = slist[w][k + 1];
            const int j2 = slist[w][k + 2], j3 = slist[w][k + 3];
            const float a0 = X[(size_t)j0 * DDIM + lane];
            const float a1 = X[(size_t)j1 * DDIM + lane];
            const float a2 = X[(size_t)j2 * DDIM + lane];
            const float a3 = X[(size_t)j3 * DDIM + lane];
            acc += (a0 + a1) + (a2 + a3);
        }
        for (; k < cn; ++k) acc += X[(size_t)slist[w][k] * DDIM + lane];

        const float xi = X[(size_t)row * DDIM + lane];
        const float h  = (acc + xi) / ((float)nnz + 1.0f);   // deg = rowsum+1 >= 1
        scat[w][lane]        = xi;
        scat[w][DDIM + lane] = h;
        __builtin_amdgcn_wave_barrier();

        // ---- GEMV: z[d] = b[d] + sum_k cat[k] * W[k][d]; W reads are L1/L2-hot.
        float z0 = bv, z1 = 0.0f, z2 = 0.0f, z3 = 0.0f;
#pragma unroll 8
        for (int kk = 0; kk < 2 * DDIM; kk += 4) {
            z0 = fmaf(scat[w][kk + 0], W[(kk + 0) * DDIM + lane], z0);
            z1 = fmaf(scat[w][kk + 1], W[(kk + 1) * DDIM + lane], z1);
            z2 = fmaf(scat[w][kk + 2], W[(kk + 2) * DDIM + lane], z2);
            z3 = fmaf(scat[w][kk + 3], W[(kk + 3) * DDIM + lane], z3);
        }
        float z = (z0 + z1) + (z2 + z3);
        z = fmaxf(z, 0.0f);

        // ---- Row L2-norm over the 64 lanes, normalize, store.
        float s2 = z * z;
#pragma unroll
        for (int off = 32; off >= 1; off >>= 1) s2 += __shfl_xor(s2, off);
        const float inv = 1.0f / fmaxf(sqrtf(s2), 1e-12f);
        out[(size_t)row * DDIM + lane] = z * inv;
    }
}

extern "C" void kernel_launch(void* const* d_in, const int* in_sizes, int n_in,
                              void* d_out, int out_size, void* d_ws, size_t ws_size,
                              hipStream_t stream) {
    const float* X   = (const float*)d_in[0];
    const float* adj = (const float*)d_in[1];
    const float* W   = (const float*)d_in[2];
    const float* b   = (const float*)d_in[3];
    float* out = (float*)d_out;
    sage_fused<<<NBLOCKS, 256, 0, stream>>>(X, adj, W, b, out);
}

// Round 5
// 1292.400 us; speedup vs baseline: 1.0432x; 1.0344x over previous
//
#include <hip/hip_runtime.h>
#include <stdint.h>

// GraphSAGE fused layer, MI355X (gfx950). All tensors fp32.
// N=16384, D=64. adj = binary fp32 mask (1.074 GB) -> stream once, floor ~170us.
// R4 insight: dur_us includes ~1.02 ms of harness reset work; kernel itself was
// ~315 us (3.4 TB/s on adj) in BOTH prior designs. Theory: 64-KB power-of-2
// row stride + lockstep wave progress => HBM channel hotspotting. Fix: each
// wave scans its row starting at a staggered 4-KB stage, wrapping mod 16, so
// instantaneous addresses cover the full 64-KB interleave span.
// One wave per row: 4096 blocks x 4 waves = 16384 waves. No __syncthreads.

#define NROWS   16384
#define DDIM    64
#define MAXNNZ  256       // deg ~ Binom(16384, 32/16384): mean 32, sigma 5.7
#define NBLOCKS 4096

typedef uint32_t u32x4 __attribute__((ext_vector_type(4)));

__global__ __launch_bounds__(256, 4) void sage_fused(
    const float* __restrict__ X,     // (N, 64)
    const float* __restrict__ adj,   // (N, N)
    const float* __restrict__ W,     // (128, 64) row-major, L2-hot (32 KB)
    const float* __restrict__ bias,  // (64,)
    float* __restrict__ out)         // (N, 64)
{
    __shared__ int   slist[4][MAXNNZ];   // per-wave nonzero column list
    __shared__ int   scnt[4];
    __shared__ float scat[4][2 * DDIM];  // per-wave [x_i | h_neigh]

    const int tid  = threadIdx.x;
    const int lane = tid & 63;
    const int w    = tid >> 6;
    const int row  = blockIdx.x * 4 + w;     // one wave per row

    const float bv = bias[lane];

    if (lane == 0) scnt[w] = 0;
    __builtin_amdgcn_wave_barrier();

    // ---- Scan the 64 KB adj row: 16 stages x (4 x 16B/lane), depth-2 pipeline.
    // Staggered start stage breaks cross-wave lockstep on the 64-KB stride.
    const int start = (row * 7 + (row >> 4)) & 15;
    const u32x4* rowp = reinterpret_cast<const u32x4*>(adj + (size_t)row * NROWS);

    u32x4 buf[2][4];
    {
        const int ss0 = start;                 // stage 0
        const int ss1 = (start + 1) & 15;      // stage 1
#pragma unroll
        for (int q = 0; q < 4; ++q)
            buf[0][q] = __builtin_nontemporal_load(&rowp[ss0 * 256 + q * 64 + lane]);
#pragma unroll
        for (int q = 0; q < 4; ++q)
            buf[1][q] = __builtin_nontemporal_load(&rowp[ss1 * 256 + q * 64 + lane]);
    }

#pragma unroll 2
    for (int s = 0; s < 16; ++s) {
        const int cur = s & 1;
        const int ss  = (s + start) & 15;      // stage being processed
        // Process current stage (compiler can wait vmcnt(4): other buf in flight).
#pragma unroll
        for (int q = 0; q < 4; ++q) {
            const u32x4 vv = buf[cur][q];
            if (vv.x | vv.y | vv.z | vv.w) {          // fp32 0.0f == all-zero bits
                const int base = (ss * 256 + q * 64 + lane) * 4;
                const uint32_t w4[4] = { vv.x, vv.y, vv.z, vv.w };
#pragma unroll
                for (int j = 0; j < 4; ++j) {
                    if (w4[j]) {
                        const int p = atomicAdd(&scnt[w], 1);
                        if (p < MAXNNZ) slist[w][p] = base + j;
                    }
                }
            }
        }
        // Refill this buffer with stage s+2.
        if (s < 14) {
            const int ssn = (s + 2 + start) & 15;
#pragma unroll
            for (int q = 0; q < 4; ++q)
                buf[cur][q] = __builtin_nontemporal_load(&rowp[ssn * 256 + q * 64 + lane]);
        }
    }
    __builtin_amdgcn_wave_barrier();

    const int nnz = scnt[w];               // DS ops in-order within the wave
    const int cn  = (nnz < MAXNNZ) ? nnz : MAXNNZ;

    // ---- Gather-accumulate neighbor X rows (256 B coalesced reads, cache-hot).
    float acc = 0.0f;
    int k = 0;
    for (; k + 4 <= cn; k += 4) {
        const int j0 = slist[w][k], j1 = slist[w][k + 1];
        const int j2 = slist[w][k + 2], j3 = slist[w][k + 3];
        const float a0 = X[(size_t)j0 * DDIM + lane];
        const float a1 = X[(size_t)j1 * DDIM + lane];
        const float a2 = X[(size_t)j2 * DDIM + lane];
        const float a3 = X[(size_t)j3 * DDIM + lane];
        acc += (a0 + a1) + (a2 + a3);
    }
    for (; k < cn; ++k) acc += X[(size_t)slist[w][k] * DDIM + lane];

    const float xi = X[(size_t)row * DDIM + lane];
    const float h  = (acc + xi) / ((float)nnz + 1.0f);   // deg = rowsum+1 >= 1
    scat[w][lane]        = xi;
    scat[w][DDIM + lane] = h;
    __builtin_amdgcn_wave_barrier();

    // ---- GEMV: z[d] = b[d] + sum_k cat[k] * W[k][d]; W is L1/L2-hot.
    float z0 = bv, z1 = 0.0f, z2 = 0.0f, z3 = 0.0f;
#pragma unroll 8
    for (int kk = 0; kk < 2 * DDIM; kk += 4) {
        z0 = fmaf(scat[w][kk + 0], W[(kk + 0) * DDIM + lane], z0);
        z1 = fmaf(scat[w][kk + 1], W[(kk + 1) * DDIM + lane], z1);
        z2 = fmaf(scat[w][kk + 2], W[(kk + 2) * DDIM + lane], z2);
        z3 = fmaf(scat[w][kk + 3], W[(kk + 3) * DDIM + lane], z3);
    }
    float z = (z0 + z1) + (z2 + z3);
    z = fmaxf(z, 0.0f);

    // ---- Row L2-norm over the 64 lanes, normalize, store.
    float s2 = z * z;
#pragma unroll
    for (int off = 32; off >= 1; off >>= 1) s2 += __shfl_xor(s2, off);
    const float inv = 1.0f / fmaxf(sqrtf(s2), 1e-12f);
    out[(size_t)row * DDIM + lane] = z * inv;
}

extern "C" void kernel_launch(void* const* d_in, const int* in_sizes, int n_in,
                              void* d_out, int out_size, void* d_ws, size_t ws_size,
                              hipStream_t stream) {
    const float* X   = (const float*)d_in[0];
    const float* adj = (const float*)d_in[1];
    const float* W   = (const float*)d_in[2];
    const float* b   = (const float*)d_in[3];
    float* out = (float*)d_out;
    sage_fused<<<NBLOCKS, 256, 0, stream>>>(X, adj, W, b, out);
}